// Round 12
// baseline (197.848 us; speedup 1.0000x reference)
//
#include <hip/hip_runtime.h>
#include <float.h>

#define L_TOK 65536
#define DIM   64
#define NCODE 1024

// ---------------------------------------------------------------------------
// Kernel A: per-code ||e||^2 (fp32), sequential-k chain.
// ---------------------------------------------------------------------------
__global__ __launch_bounds__(256) void esum_kernel(const float* __restrict__ emb,
                                                   float* __restrict__ esum) {
    int n = blockIdx.x * 256 + threadIdx.x;
    if (n >= NCODE) return;
    const float* e = emb + ((size_t)n << 6);
    float s = 0.f;
#pragma unroll
    for (int k = 0; k < DIM; ++k) s = fmaf(e[k], e[k], s);
    esum[n] = s;
}

// ---------------------------------------------------------------------------
// Kernel B: argmin. Geometry matrix (measured):
//   r9:  2 tok/lane, 4 w/SIMD, VGPR 48 clean          -> 143us
//   r10: 4 tok/lane, 4 w/SIMD, VGPR 64 + 17.7MB spill -> 190us
//   r11: 4 tok/lane, 2 w/SIMD, VGPR 96 clean          -> 169us
// Missing cell: 4 tok/lane + 4 w/SIMD + clean ~96 VGPR. r10 failed ONLY on
// allocation: launch_bounds(1024,4) is a MINIMUM waves/EU, allocator still
// targeted 8 w/EU (64-VGPR budget) ignoring the 96KB-LDS 1-block/CU cap.
// Fix: amdgpu_waves_per_eu(4,4) pins the target -> 128-VGPR budget, zero
// occupancy cost (LDS already caps at 4 w/SIMD). Per chunk, the structural
// lgkmcnt(0) drain (SMEM completes out-of-order) is amortized over 256
// fmac-cycles (2x r9), and 4 waves/SIMD cover the residual.
// Numerics bitwise-identical (r10 passed absmax 0.0; body unchanged):
// per-(token,code) sequential k=0..63 fmaf chains, d = fmaf(a,-2,zs+esum),
// ascending strict '<', ascending-wave lowest-index merge == np.argmin.
// ---------------------------------------------------------------------------
__global__ __launch_bounds__(1024)
__attribute__((amdgpu_waves_per_eu(4, 4)))
void argmin_kernel(const float* __restrict__ z,
                   const float* __restrict__ emb,
                   const float* __restrict__ esum,
                   float* __restrict__ idx_out) {
    __shared__ float zl[256 * 64];    // swizzled row-major [tok][k], 64 KB
    __shared__ float sb[16][256];     // 16 KB
    __shared__ int   si[16][256];     // 16 KB

    const int t    = threadIdx.x;
    const int lane = t & 63;
    const int wid  = __builtin_amdgcn_readfirstlane(t >> 6);
    char* zbytes   = (char*)zl;

    // Stage z tile: 256 rows; each thread stages 16 consecutive floats of one
    // row (4 float4s), coalesced global read, swizzled LDS writes.
    {
        const int tok = t >> 2;            // 0..255
        const int kk  = (t & 3) * 16;      // 0,16,32,48
        const int swt = (tok & 15) << 4;
        const float* src = z + ((size_t)(blockIdx.x * 256 + tok) << 6) + kk;
        float4 v0 = ((const float4*)src)[0];
        float4 v1 = ((const float4*)src)[1];
        float4 v2 = ((const float4*)src)[2];
        float4 v3 = ((const float4*)src)[3];
        *(float4*)(zbytes + tok * 256 + (((kk +  0) * 4) ^ swt)) = v0;
        *(float4*)(zbytes + tok * 256 + (((kk +  4) * 4) ^ swt)) = v1;
        *(float4*)(zbytes + tok * 256 + (((kk +  8) * 4) ^ swt)) = v2;
        *(float4*)(zbytes + tok * 256 + (((kk + 12) * 4) ^ swt)) = v3;
    }
    __syncthreads();

    const int rbA = lane * 256;            // token A = lane
    const int rbB = rbA + 64 * 256;        // token B = lane + 64
    const int rbC = rbA + 128 * 256;       // token C = lane + 128
    const int rbD = rbA + 192 * 256;       // token D = lane + 192
    const int sw  = (lane & 15) << 4;      // (lane+64m)&15 == lane&15

    // ||z||^2 per token, sequential k (chunk-ascending, x,y,z,w order).
    float zsA = 0.f, zsB = 0.f, zsC = 0.f, zsD = 0.f;
#pragma unroll
    for (int k0 = 0; k0 < 64; k0 += 4) {
        float4 a = *(const float4*)(zbytes + rbA + ((k0 * 4) ^ sw));
        float4 b = *(const float4*)(zbytes + rbB + ((k0 * 4) ^ sw));
        float4 c = *(const float4*)(zbytes + rbC + ((k0 * 4) ^ sw));
        float4 d = *(const float4*)(zbytes + rbD + ((k0 * 4) ^ sw));
        zsA = fmaf(a.x, a.x, zsA); zsA = fmaf(a.y, a.y, zsA);
        zsA = fmaf(a.z, a.z, zsA); zsA = fmaf(a.w, a.w, zsA);
        zsB = fmaf(b.x, b.x, zsB); zsB = fmaf(b.y, b.y, zsB);
        zsB = fmaf(b.z, b.z, zsB); zsB = fmaf(b.w, b.w, zsB);
        zsC = fmaf(c.x, c.x, zsC); zsC = fmaf(c.y, c.y, zsC);
        zsC = fmaf(c.z, c.z, zsC); zsC = fmaf(c.w, c.w, zsC);
        zsD = fmaf(d.x, d.x, zsD); zsD = fmaf(d.y, d.y, zsD);
        zsD = fmaf(d.z, d.z, zsD); zsD = fmaf(d.w, d.w, zsD);
    }

    float bestA = FLT_MAX, bestB = FLT_MAX, bestC = FLT_MAX, bestD = FLT_MAX;
    int   biA   = 0,       biB   = 0,       biC   = 0,       biD   = 0;
    const int cbase = wid * 64;            // wave-uniform

    for (int c0 = cbase; c0 < cbase + 64; c0 += 8) {
        int szero = 0;
        asm volatile("" : "+s"(szero));    // opaque per-iter def: blocks LICM
        const int rA = rbA + szero;
        const int rB = rbB + szero;
        const int rC = rbC + szero;
        const int rD = rbD + szero;

        const float* __restrict__ e0 = emb + ((size_t)(c0 + 0) << 6);
        const float* __restrict__ e1 = emb + ((size_t)(c0 + 1) << 6);
        const float* __restrict__ e2 = emb + ((size_t)(c0 + 2) << 6);
        const float* __restrict__ e3 = emb + ((size_t)(c0 + 3) << 6);
        const float* __restrict__ e4 = emb + ((size_t)(c0 + 4) << 6);
        const float* __restrict__ e5 = emb + ((size_t)(c0 + 5) << 6);
        const float* __restrict__ e6 = emb + ((size_t)(c0 + 6) << 6);
        const float* __restrict__ e7 = emb + ((size_t)(c0 + 7) << 6);
        float a0 = 0.f, a1 = 0.f, a2 = 0.f, a3 = 0.f;
        float a4 = 0.f, a5 = 0.f, a6 = 0.f, a7 = 0.f;
        float b0 = 0.f, b1 = 0.f, b2 = 0.f, b3 = 0.f;
        float b4 = 0.f, b5 = 0.f, b6 = 0.f, b7 = 0.f;
        float c0a = 0.f, c1a = 0.f, c2a = 0.f, c3a = 0.f;
        float c4a = 0.f, c5a = 0.f, c6a = 0.f, c7a = 0.f;
        float d0a = 0.f, d1a = 0.f, d2a = 0.f, d3a = 0.f;
        float d4a = 0.f, d5a = 0.f, d6a = 0.f, d7a = 0.f;
#pragma unroll
        for (int k0 = 0; k0 < 64; k0 += 4) {
            float4 za = *(const float4*)(zbytes + rA + ((k0 * 4) ^ sw));
            float4 zb = *(const float4*)(zbytes + rB + ((k0 * 4) ^ sw));
            float4 zc = *(const float4*)(zbytes + rC + ((k0 * 4) ^ sw));
            float4 zd = *(const float4*)(zbytes + rD + ((k0 * 4) ^ sw));
            float4 f0 = *(const float4*)(e0 + k0);
            float4 f1 = *(const float4*)(e1 + k0);
            float4 f2 = *(const float4*)(e2 + k0);
            float4 f3 = *(const float4*)(e3 + k0);
            float4 f4 = *(const float4*)(e4 + k0);
            float4 f5 = *(const float4*)(e5 + k0);
            float4 f6 = *(const float4*)(e6 + k0);
            float4 f7 = *(const float4*)(e7 + k0);
            a0 = fmaf(za.x, f0.x, a0); a0 = fmaf(za.y, f0.y, a0);
            a0 = fmaf(za.z, f0.z, a0); a0 = fmaf(za.w, f0.w, a0);
            a1 = fmaf(za.x, f1.x, a1); a1 = fmaf(za.y, f1.y, a1);
            a1 = fmaf(za.z, f1.z, a1); a1 = fmaf(za.w, f1.w, a1);
            a2 = fmaf(za.x, f2.x, a2); a2 = fmaf(za.y, f2.y, a2);
            a2 = fmaf(za.z, f2.z, a2); a2 = fmaf(za.w, f2.w, a2);
            a3 = fmaf(za.x, f3.x, a3); a3 = fmaf(za.y, f3.y, a3);
            a3 = fmaf(za.z, f3.z, a3); a3 = fmaf(za.w, f3.w, a3);
            a4 = fmaf(za.x, f4.x, a4); a4 = fmaf(za.y, f4.y, a4);
            a4 = fmaf(za.z, f4.z, a4); a4 = fmaf(za.w, f4.w, a4);
            a5 = fmaf(za.x, f5.x, a5); a5 = fmaf(za.y, f5.y, a5);
            a5 = fmaf(za.z, f5.z, a5); a5 = fmaf(za.w, f5.w, a5);
            a6 = fmaf(za.x, f6.x, a6); a6 = fmaf(za.y, f6.y, a6);
            a6 = fmaf(za.z, f6.z, a6); a6 = fmaf(za.w, f6.w, a6);
            a7 = fmaf(za.x, f7.x, a7); a7 = fmaf(za.y, f7.y, a7);
            a7 = fmaf(za.z, f7.z, a7); a7 = fmaf(za.w, f7.w, a7);
            b0 = fmaf(zb.x, f0.x, b0); b0 = fmaf(zb.y, f0.y, b0);
            b0 = fmaf(zb.z, f0.z, b0); b0 = fmaf(zb.w, f0.w, b0);
            b1 = fmaf(zb.x, f1.x, b1); b1 = fmaf(zb.y, f1.y, b1);
            b1 = fmaf(zb.z, f1.z, b1); b1 = fmaf(zb.w, f1.w, b1);
            b2 = fmaf(zb.x, f2.x, b2); b2 = fmaf(zb.y, f2.y, b2);
            b2 = fmaf(zb.z, f2.z, b2); b2 = fmaf(zb.w, f2.w, b2);
            b3 = fmaf(zb.x, f3.x, b3); b3 = fmaf(zb.y, f3.y, b3);
            b3 = fmaf(zb.z, f3.z, b3); b3 = fmaf(zb.w, f3.w, b3);
            b4 = fmaf(zb.x, f4.x, b4); b4 = fmaf(zb.y, f4.y, b4);
            b4 = fmaf(zb.z, f4.z, b4); b4 = fmaf(zb.w, f4.w, b4);
            b5 = fmaf(zb.x, f5.x, b5); b5 = fmaf(zb.y, f5.y, b5);
            b5 = fmaf(zb.z, f5.z, b5); b5 = fmaf(zb.w, f5.w, b5);
            b6 = fmaf(zb.x, f6.x, b6); b6 = fmaf(zb.y, f6.y, b6);
            b6 = fmaf(zb.z, f6.z, b6); b6 = fmaf(zb.w, f6.w, b6);
            b7 = fmaf(zb.x, f7.x, b7); b7 = fmaf(zb.y, f7.y, b7);
            b7 = fmaf(zb.z, f7.z, b7); b7 = fmaf(zb.w, f7.w, b7);
            c0a = fmaf(zc.x, f0.x, c0a); c0a = fmaf(zc.y, f0.y, c0a);
            c0a = fmaf(zc.z, f0.z, c0a); c0a = fmaf(zc.w, f0.w, c0a);
            c1a = fmaf(zc.x, f1.x, c1a); c1a = fmaf(zc.y, f1.y, c1a);
            c1a = fmaf(zc.z, f1.z, c1a); c1a = fmaf(zc.w, f1.w, c1a);
            c2a = fmaf(zc.x, f2.x, c2a); c2a = fmaf(zc.y, f2.y, c2a);
            c2a = fmaf(zc.z, f2.z, c2a); c2a = fmaf(zc.w, f2.w, c2a);
            c3a = fmaf(zc.x, f3.x, c3a); c3a = fmaf(zc.y, f3.y, c3a);
            c3a = fmaf(zc.z, f3.z, c3a); c3a = fmaf(zc.w, f3.w, c3a);
            c4a = fmaf(zc.x, f4.x, c4a); c4a = fmaf(zc.y, f4.y, c4a);
            c4a = fmaf(zc.z, f4.z, c4a); c4a = fmaf(zc.w, f4.w, c4a);
            c5a = fmaf(zc.x, f5.x, c5a); c5a = fmaf(zc.y, f5.y, c5a);
            c5a = fmaf(zc.z, f5.z, c5a); c5a = fmaf(zc.w, f5.w, c5a);
            c6a = fmaf(zc.x, f6.x, c6a); c6a = fmaf(zc.y, f6.y, c6a);
            c6a = fmaf(zc.z, f6.z, c6a); c6a = fmaf(zc.w, f6.w, c6a);
            c7a = fmaf(zc.x, f7.x, c7a); c7a = fmaf(zc.y, f7.y, c7a);
            c7a = fmaf(zc.z, f7.z, c7a); c7a = fmaf(zc.w, f7.w, c7a);
            d0a = fmaf(zd.x, f0.x, d0a); d0a = fmaf(zd.y, f0.y, d0a);
            d0a = fmaf(zd.z, f0.z, d0a); d0a = fmaf(zd.w, f0.w, d0a);
            d1a = fmaf(zd.x, f1.x, d1a); d1a = fmaf(zd.y, f1.y, d1a);
            d1a = fmaf(zd.z, f1.z, d1a); d1a = fmaf(zd.w, f1.w, d1a);
            d2a = fmaf(zd.x, f2.x, d2a); d2a = fmaf(zd.y, f2.y, d2a);
            d2a = fmaf(zd.z, f2.z, d2a); d2a = fmaf(zd.w, f2.w, d2a);
            d3a = fmaf(zd.x, f3.x, d3a); d3a = fmaf(zd.y, f3.y, d3a);
            d3a = fmaf(zd.z, f3.z, d3a); d3a = fmaf(zd.w, f3.w, d3a);
            d4a = fmaf(zd.x, f4.x, d4a); d4a = fmaf(zd.y, f4.y, d4a);
            d4a = fmaf(zd.z, f4.z, d4a); d4a = fmaf(zd.w, f4.w, d4a);
            d5a = fmaf(zd.x, f5.x, d5a); d5a = fmaf(zd.y, f5.y, d5a);
            d5a = fmaf(zd.z, f5.z, d5a); d5a = fmaf(zd.w, f5.w, d5a);
            d6a = fmaf(zd.x, f6.x, d6a); d6a = fmaf(zd.y, f6.y, d6a);
            d6a = fmaf(zd.z, f6.z, d6a); d6a = fmaf(zd.w, f6.w, d6a);
            d7a = fmaf(zd.x, f7.x, d7a); d7a = fmaf(zd.y, f7.y, d7a);
            d7a = fmaf(zd.z, f7.z, d7a); d7a = fmaf(zd.w, f7.w, d7a);
        }
#pragma unroll
        for (int j = 0; j < 8; ++j) {
            float aj = (j==0?a0:j==1?a1:j==2?a2:j==3?a3:j==4?a4:j==5?a5:j==6?a6:a7);
            float bj = (j==0?b0:j==1?b1:j==2?b2:j==3?b3:j==4?b4:j==5?b5:j==6?b6:b7);
            float cj = (j==0?c0a:j==1?c1a:j==2?c2a:j==3?c3a:j==4?c4a:j==5?c5a:j==6?c6a:c7a);
            float dj = (j==0?d0a:j==1?d1a:j==2?d2a:j==3?d3a:j==4?d4a:j==5?d5a:j==6?d6a:d7a);
            float es = esum[c0 + j];
            float dA = fmaf(aj, -2.0f, zsA + es);
            float dB = fmaf(bj, -2.0f, zsB + es);
            float dC = fmaf(cj, -2.0f, zsC + es);
            float dD = fmaf(dj, -2.0f, zsD + es);
            if (dA < bestA) { bestA = dA; biA = c0 + j; }
            if (dB < bestB) { bestB = dB; biB = c0 + j; }
            if (dC < bestC) { bestC = dC; biC = c0 + j; }
            if (dD < bestD) { bestD = dD; biD = c0 + j; }
        }
    }

    sb[wid][lane]       = bestA;  si[wid][lane]       = biA;
    sb[wid][lane + 64]  = bestB;  si[wid][lane + 64]  = biB;
    sb[wid][lane + 128] = bestC;  si[wid][lane + 128] = biC;
    sb[wid][lane + 192] = bestD;  si[wid][lane + 192] = biD;
    __syncthreads();

    if (t < 256) {
        float b = sb[0][t];
        int   i = si[0][t];
#pragma unroll
        for (int w = 1; w < 16; ++w) {
            float ob = sb[w][t];
            int   oi = si[w][t];
            if (ob < b || (ob == b && oi < i)) { b = ob; i = oi; }
        }
        idx_out[blockIdx.x * 256 + t] = (float)i;
    }
}

// ---------------------------------------------------------------------------
// Kernel C: z_q_st + per-block f64 loss partials (unchanged).
// ---------------------------------------------------------------------------
__global__ __launch_bounds__(256) void output_kernel(const float* __restrict__ z,
                                                     const float* __restrict__ emb,
                                                     const float* __restrict__ idx_f,
                                                     float* __restrict__ zq_out,
                                                     double* __restrict__ partials) {
    int gid = blockIdx.x * 256 + threadIdx.x;
    int l = gid >> 6;
    int k = gid & 63;
    int idx = (int)idx_f[l];

    float zv = z[gid];
    float ev = emb[(idx << 6) + k];
    float t    = ev - zv;
    float outv = zv + t;
    zq_out[gid] = outv;

    float sq = t * t;

    __shared__ double red[256];
    red[threadIdx.x] = (double)sq;
    __syncthreads();
    for (int s = 128; s > 0; s >>= 1) {
        if (threadIdx.x < s) red[threadIdx.x] += red[threadIdx.x + s];
        __syncthreads();
    }
    if (threadIdx.x == 0) partials[blockIdx.x] = red[0];
}

// ---------------------------------------------------------------------------
// Kernel D: final deterministic reduction (unchanged).
// ---------------------------------------------------------------------------
__global__ __launch_bounds__(256) void loss_kernel(const double* __restrict__ partials,
                                                   float* __restrict__ loss_out) {
    __shared__ double red[256];
    int t = threadIdx.x;
    double s = 0.0;
    for (int i = 0; i < 64; ++i) s += partials[t * 64 + i];
    red[t] = s;
    __syncthreads();
    for (int st = 128; st > 0; st >>= 1) {
        if (t < st) red[t] += red[t + st];
        __syncthreads();
    }
    if (t == 0) {
        double m  = red[0] / (double)(L_TOK * DIM);
        float  mf = (float)m;
        loss_out[0] = 0.25f * mf + mf;
    }
}

extern "C" void kernel_launch(void* const* d_in, const int* in_sizes, int n_in,
                              void* d_out, int out_size, void* d_ws, size_t ws_size,
                              hipStream_t stream) {
    const float* z   = (const float*)d_in[0];
    const float* emb = (const float*)d_in[1];

    float* out   = (float*)d_out;
    float* zq    = out;                 // [0, 4194304)
    float* loss  = out + 4194304;       // [4194304]
    float* idxf  = out + 4194305;       // [4194305, 4259841)

    float*  esum     = (float*)d_ws;                          // 1024 f32
    double* partials = (double*)((char*)d_ws + 8192);         // 16384 f64

    esum_kernel  <<<4,     256, 0, stream>>>(emb, esum);
    argmin_kernel<<<256,  1024, 0, stream>>>(z, emb, esum, idxf);
    output_kernel<<<16384, 256, 0, stream>>>(z, emb, idxf, zq, partials);
    loss_kernel  <<<1,     256, 0, stream>>>(partials, loss);
}

// Round 13
// 147.109 us; speedup vs baseline: 1.3449x; 1.3449x over previous
//
#include <hip/hip_runtime.h>
#include <float.h>

#define L_TOK 65536
#define DIM   64
#define NCODE 1024

// ---------------------------------------------------------------------------
// Kernel A: per-code ||e||^2 (fp32), sequential-k chain.
// ---------------------------------------------------------------------------
__global__ __launch_bounds__(256) void esum_kernel(const float* __restrict__ emb,
                                                   float* __restrict__ esum) {
    int n = blockIdx.x * 256 + threadIdx.x;
    if (n >= NCODE) return;
    const float* e = emb + ((size_t)n << 6);
    float s = 0.f;
#pragma unroll
    for (int k = 0; k < DIM; ++k) s = fmaf(e[k], e[k], s);
    esum[n] = s;
}

// ---------------------------------------------------------------------------
// Kernel B: argmin. Geometry matrix (measured):
//   r9:  2 tok/lane, 4 w/SIMD, VGPR 48 clean           -> 143us
//   r10/r12: 4 tok/lane, 1024thr: allocator hard-caps 64 VGPR (attributes
//        ignored) -> 17.7MB scratch -> 190us. 1024-thr route dead.
//   r11: 4 tok/lane, 512thr, LB(512,2), VGPR 96 clean, but 80KB LDS +
//        grid 256 -> 1 block/CU = 2 w/SIMD -> 169us (stall-dominated).
// This round: same r11 body, occupancy doubled via CODE-SPLIT:
//   512 blocks x 512 thr; block b = token-tile (b>>1) x code-half (b&1).
//   Wave w covers codes [half*512 + w*64, +64) (8 chunks). Total per-CU
//   work unchanged; 2 blocks/CU -> 4 w/SIMD. LDS trimmed to the 64KB
//   z-tile (merge reuses it after syncthreads) -> 128KB/CU fits 2 blocks.
//   Per-half (best,idx) -> workspace; merge kernel takes half-0 on ties
//   (half0 = lower code indices == np.argmin first-wins).
// Numerics bitwise-identical to r11 (absmax 0.0).
// ---------------------------------------------------------------------------
__global__ __launch_bounds__(512, 2) void argmin_kernel(const float* __restrict__ z,
                                                        const float* __restrict__ emb,
                                                        const float* __restrict__ esum,
                                                        float* __restrict__ dbest,
                                                        int* __restrict__ ibest) {
    __shared__ float zl[256 * 64];    // swizzled row-major [tok][k], 64 KB
                                      // (reused for the cross-wave merge)
    const int t    = threadIdx.x;
    const int lane = t & 63;
    const int wid  = __builtin_amdgcn_readfirstlane(t >> 6);
    char* zbytes   = (char*)zl;

    const int tokbase = (blockIdx.x >> 1) * 256;
    const int half    = blockIdx.x & 1;

    // Stage z tile: 256 rows; each thread stages 32 consecutive floats of one
    // row (8 float4s), coalesced global read, swizzled LDS writes.
    {
        const int tok = t >> 1;            // 0..255
        const int kk  = (t & 1) * 32;      // 0 or 32
        const int swt = (tok & 15) << 4;
        const float* src = z + ((size_t)(tokbase + tok) << 6) + kk;
#pragma unroll
        for (int i = 0; i < 8; ++i) {
            float4 v = ((const float4*)src)[i];
            *(float4*)(zbytes + tok * 256 + (((kk + 4*i) * 4) ^ swt)) = v;
        }
    }
    __syncthreads();

    const int rbA = lane * 256;            // token A = lane
    const int rbB = rbA + 64 * 256;        // token B = lane + 64
    const int rbC = rbA + 128 * 256;       // token C = lane + 128
    const int rbD = rbA + 192 * 256;       // token D = lane + 192
    const int sw  = (lane & 15) << 4;      // (lane+64m)&15 == lane&15

    // ||z||^2 per token, sequential k (chunk-ascending, x,y,z,w order).
    float zsA = 0.f, zsB = 0.f, zsC = 0.f, zsD = 0.f;
#pragma unroll
    for (int k0 = 0; k0 < 64; k0 += 4) {
        float4 a = *(const float4*)(zbytes + rbA + ((k0 * 4) ^ sw));
        float4 b = *(const float4*)(zbytes + rbB + ((k0 * 4) ^ sw));
        float4 c = *(const float4*)(zbytes + rbC + ((k0 * 4) ^ sw));
        float4 d = *(const float4*)(zbytes + rbD + ((k0 * 4) ^ sw));
        zsA = fmaf(a.x, a.x, zsA); zsA = fmaf(a.y, a.y, zsA);
        zsA = fmaf(a.z, a.z, zsA); zsA = fmaf(a.w, a.w, zsA);
        zsB = fmaf(b.x, b.x, zsB); zsB = fmaf(b.y, b.y, zsB);
        zsB = fmaf(b.z, b.z, zsB); zsB = fmaf(b.w, b.w, zsB);
        zsC = fmaf(c.x, c.x, zsC); zsC = fmaf(c.y, c.y, zsC);
        zsC = fmaf(c.z, c.z, zsC); zsC = fmaf(c.w, c.w, zsC);
        zsD = fmaf(d.x, d.x, zsD); zsD = fmaf(d.y, d.y, zsD);
        zsD = fmaf(d.z, d.z, zsD); zsD = fmaf(d.w, d.w, zsD);
    }

    float bestA = FLT_MAX, bestB = FLT_MAX, bestC = FLT_MAX, bestD = FLT_MAX;
    int   biA   = 0,       biB   = 0,       biC   = 0,       biD   = 0;
    const int cbase = half * 512 + wid * 64;   // wave-uniform

    for (int c0 = cbase; c0 < cbase + 64; c0 += 8) {
        int szero = 0;
        asm volatile("" : "+s"(szero));    // opaque per-iter def: blocks LICM
        const int rA = rbA + szero;
        const int rB = rbB + szero;
        const int rC = rbC + szero;
        const int rD = rbD + szero;

        const float* __restrict__ e0 = emb + ((size_t)(c0 + 0) << 6);
        const float* __restrict__ e1 = emb + ((size_t)(c0 + 1) << 6);
        const float* __restrict__ e2 = emb + ((size_t)(c0 + 2) << 6);
        const float* __restrict__ e3 = emb + ((size_t)(c0 + 3) << 6);
        const float* __restrict__ e4 = emb + ((size_t)(c0 + 4) << 6);
        const float* __restrict__ e5 = emb + ((size_t)(c0 + 5) << 6);
        const float* __restrict__ e6 = emb + ((size_t)(c0 + 6) << 6);
        const float* __restrict__ e7 = emb + ((size_t)(c0 + 7) << 6);
        float a0 = 0.f, a1 = 0.f, a2 = 0.f, a3 = 0.f;
        float a4 = 0.f, a5 = 0.f, a6 = 0.f, a7 = 0.f;
        float b0 = 0.f, b1 = 0.f, b2 = 0.f, b3 = 0.f;
        float b4 = 0.f, b5 = 0.f, b6 = 0.f, b7 = 0.f;
        float c0a = 0.f, c1a = 0.f, c2a = 0.f, c3a = 0.f;
        float c4a = 0.f, c5a = 0.f, c6a = 0.f, c7a = 0.f;
        float d0a = 0.f, d1a = 0.f, d2a = 0.f, d3a = 0.f;
        float d4a = 0.f, d5a = 0.f, d6a = 0.f, d7a = 0.f;
#pragma unroll
        for (int k0 = 0; k0 < 64; k0 += 4) {
            float4 za = *(const float4*)(zbytes + rA + ((k0 * 4) ^ sw));
            float4 zb = *(const float4*)(zbytes + rB + ((k0 * 4) ^ sw));
            float4 zc = *(const float4*)(zbytes + rC + ((k0 * 4) ^ sw));
            float4 zd = *(const float4*)(zbytes + rD + ((k0 * 4) ^ sw));
            float4 f0 = *(const float4*)(e0 + k0);
            float4 f1 = *(const float4*)(e1 + k0);
            float4 f2 = *(const float4*)(e2 + k0);
            float4 f3 = *(const float4*)(e3 + k0);
            float4 f4 = *(const float4*)(e4 + k0);
            float4 f5 = *(const float4*)(e5 + k0);
            float4 f6 = *(const float4*)(e6 + k0);
            float4 f7 = *(const float4*)(e7 + k0);
            a0 = fmaf(za.x, f0.x, a0); a0 = fmaf(za.y, f0.y, a0);
            a0 = fmaf(za.z, f0.z, a0); a0 = fmaf(za.w, f0.w, a0);
            a1 = fmaf(za.x, f1.x, a1); a1 = fmaf(za.y, f1.y, a1);
            a1 = fmaf(za.z, f1.z, a1); a1 = fmaf(za.w, f1.w, a1);
            a2 = fmaf(za.x, f2.x, a2); a2 = fmaf(za.y, f2.y, a2);
            a2 = fmaf(za.z, f2.z, a2); a2 = fmaf(za.w, f2.w, a2);
            a3 = fmaf(za.x, f3.x, a3); a3 = fmaf(za.y, f3.y, a3);
            a3 = fmaf(za.z, f3.z, a3); a3 = fmaf(za.w, f3.w, a3);
            a4 = fmaf(za.x, f4.x, a4); a4 = fmaf(za.y, f4.y, a4);
            a4 = fmaf(za.z, f4.z, a4); a4 = fmaf(za.w, f4.w, a4);
            a5 = fmaf(za.x, f5.x, a5); a5 = fmaf(za.y, f5.y, a5);
            a5 = fmaf(za.z, f5.z, a5); a5 = fmaf(za.w, f5.w, a5);
            a6 = fmaf(za.x, f6.x, a6); a6 = fmaf(za.y, f6.y, a6);
            a6 = fmaf(za.z, f6.z, a6); a6 = fmaf(za.w, f6.w, a6);
            a7 = fmaf(za.x, f7.x, a7); a7 = fmaf(za.y, f7.y, a7);
            a7 = fmaf(za.z, f7.z, a7); a7 = fmaf(za.w, f7.w, a7);
            b0 = fmaf(zb.x, f0.x, b0); b0 = fmaf(zb.y, f0.y, b0);
            b0 = fmaf(zb.z, f0.z, b0); b0 = fmaf(zb.w, f0.w, b0);
            b1 = fmaf(zb.x, f1.x, b1); b1 = fmaf(zb.y, f1.y, b1);
            b1 = fmaf(zb.z, f1.z, b1); b1 = fmaf(zb.w, f1.w, b1);
            b2 = fmaf(zb.x, f2.x, b2); b2 = fmaf(zb.y, f2.y, b2);
            b2 = fmaf(zb.z, f2.z, b2); b2 = fmaf(zb.w, f2.w, b2);
            b3 = fmaf(zb.x, f3.x, b3); b3 = fmaf(zb.y, f3.y, b3);
            b3 = fmaf(zb.z, f3.z, b3); b3 = fmaf(zb.w, f3.w, b3);
            b4 = fmaf(zb.x, f4.x, b4); b4 = fmaf(zb.y, f4.y, b4);
            b4 = fmaf(zb.z, f4.z, b4); b4 = fmaf(zb.w, f4.w, b4);
            b5 = fmaf(zb.x, f5.x, b5); b5 = fmaf(zb.y, f5.y, b5);
            b5 = fmaf(zb.z, f5.z, b5); b5 = fmaf(zb.w, f5.w, b5);
            b6 = fmaf(zb.x, f6.x, b6); b6 = fmaf(zb.y, f6.y, b6);
            b6 = fmaf(zb.z, f6.z, b6); b6 = fmaf(zb.w, f6.w, b6);
            b7 = fmaf(zb.x, f7.x, b7); b7 = fmaf(zb.y, f7.y, b7);
            b7 = fmaf(zb.z, f7.z, b7); b7 = fmaf(zb.w, f7.w, b7);
            c0a = fmaf(zc.x, f0.x, c0a); c0a = fmaf(zc.y, f0.y, c0a);
            c0a = fmaf(zc.z, f0.z, c0a); c0a = fmaf(zc.w, f0.w, c0a);
            c1a = fmaf(zc.x, f1.x, c1a); c1a = fmaf(zc.y, f1.y, c1a);
            c1a = fmaf(zc.z, f1.z, c1a); c1a = fmaf(zc.w, f1.w, c1a);
            c2a = fmaf(zc.x, f2.x, c2a); c2a = fmaf(zc.y, f2.y, c2a);
            c2a = fmaf(zc.z, f2.z, c2a); c2a = fmaf(zc.w, f2.w, c2a);
            c3a = fmaf(zc.x, f3.x, c3a); c3a = fmaf(zc.y, f3.y, c3a);
            c3a = fmaf(zc.z, f3.z, c3a); c3a = fmaf(zc.w, f3.w, c3a);
            c4a = fmaf(zc.x, f4.x, c4a); c4a = fmaf(zc.y, f4.y, c4a);
            c4a = fmaf(zc.z, f4.z, c4a); c4a = fmaf(zc.w, f4.w, c4a);
            c5a = fmaf(zc.x, f5.x, c5a); c5a = fmaf(zc.y, f5.y, c5a);
            c5a = fmaf(zc.z, f5.z, c5a); c5a = fmaf(zc.w, f5.w, c5a);
            c6a = fmaf(zc.x, f6.x, c6a); c6a = fmaf(zc.y, f6.y, c6a);
            c6a = fmaf(zc.z, f6.z, c6a); c6a = fmaf(zc.w, f6.w, c6a);
            c7a = fmaf(zc.x, f7.x, c7a); c7a = fmaf(zc.y, f7.y, c7a);
            c7a = fmaf(zc.z, f7.z, c7a); c7a = fmaf(zc.w, f7.w, c7a);
            d0a = fmaf(zd.x, f0.x, d0a); d0a = fmaf(zd.y, f0.y, d0a);
            d0a = fmaf(zd.z, f0.z, d0a); d0a = fmaf(zd.w, f0.w, d0a);
            d1a = fmaf(zd.x, f1.x, d1a); d1a = fmaf(zd.y, f1.y, d1a);
            d1a = fmaf(zd.z, f1.z, d1a); d1a = fmaf(zd.w, f1.w, d1a);
            d2a = fmaf(zd.x, f2.x, d2a); d2a = fmaf(zd.y, f2.y, d2a);
            d2a = fmaf(zd.z, f2.z, d2a); d2a = fmaf(zd.w, f2.w, d2a);
            d3a = fmaf(zd.x, f3.x, d3a); d3a = fmaf(zd.y, f3.y, d3a);
            d3a = fmaf(zd.z, f3.z, d3a); d3a = fmaf(zd.w, f3.w, d3a);
            d4a = fmaf(zd.x, f4.x, d4a); d4a = fmaf(zd.y, f4.y, d4a);
            d4a = fmaf(zd.z, f4.z, d4a); d4a = fmaf(zd.w, f4.w, d4a);
            d5a = fmaf(zd.x, f5.x, d5a); d5a = fmaf(zd.y, f5.y, d5a);
            d5a = fmaf(zd.z, f5.z, d5a); d5a = fmaf(zd.w, f5.w, d5a);
            d6a = fmaf(zd.x, f6.x, d6a); d6a = fmaf(zd.y, f6.y, d6a);
            d6a = fmaf(zd.z, f6.z, d6a); d6a = fmaf(zd.w, f6.w, d6a);
            d7a = fmaf(zd.x, f7.x, d7a); d7a = fmaf(zd.y, f7.y, d7a);
            d7a = fmaf(zd.z, f7.z, d7a); d7a = fmaf(zd.w, f7.w, d7a);
        }
#pragma unroll
        for (int j = 0; j < 8; ++j) {
            float aj = (j==0?a0:j==1?a1:j==2?a2:j==3?a3:j==4?a4:j==5?a5:j==6?a6:a7);
            float bj = (j==0?b0:j==1?b1:j==2?b2:j==3?b3:j==4?b4:j==5?b5:j==6?b6:b7);
            float cj = (j==0?c0a:j==1?c1a:j==2?c2a:j==3?c3a:j==4?c4a:j==5?c5a:j==6?c6a:c7a);
            float dj = (j==0?d0a:j==1?d1a:j==2?d2a:j==3?d3a:j==4?d4a:j==5?d5a:j==6?d6a:d7a);
            float es = esum[c0 + j];
            float dA = fmaf(aj, -2.0f, zsA + es);
            float dB = fmaf(bj, -2.0f, zsB + es);
            float dC = fmaf(cj, -2.0f, zsC + es);
            float dD = fmaf(dj, -2.0f, zsD + es);
            if (dA < bestA) { bestA = dA; biA = c0 + j; }
            if (dB < bestB) { bestB = dB; biB = c0 + j; }
            if (dC < bestC) { bestC = dC; biC = c0 + j; }
            if (dD < bestD) { bestD = dD; biD = c0 + j; }
        }
    }

    // Cross-wave merge: reuse the z LDS region (all reads of z are done).
    __syncthreads();
    float* sbf = zl;                  // [8][256] floats
    int*   sif = (int*)(zl + 2048);   // [8][256] ints
    sbf[wid * 256 + lane]       = bestA;  sif[wid * 256 + lane]       = biA;
    sbf[wid * 256 + lane + 64]  = bestB;  sif[wid * 256 + lane + 64]  = biB;
    sbf[wid * 256 + lane + 128] = bestC;  sif[wid * 256 + lane + 128] = biC;
    sbf[wid * 256 + lane + 192] = bestD;  sif[wid * 256 + lane + 192] = biD;
    __syncthreads();

    if (t < 256) {
        float b = sbf[t];
        int   i = sif[t];
#pragma unroll
        for (int w = 1; w < 8; ++w) {
            float ob = sbf[w * 256 + t];
            int   oi = sif[w * 256 + t];
            if (ob < b || (ob == b && oi < i)) { b = ob; i = oi; }
        }
        dbest[half * L_TOK + tokbase + t] = b;
        ibest[half * L_TOK + tokbase + t] = i;
    }
}

// ---------------------------------------------------------------------------
// Kernel B2: merge the two code-halves. half0 = codes [0,512) so on ties
// half0 wins == lowest index == np.argmin first-wins.
// ---------------------------------------------------------------------------
__global__ __launch_bounds__(256) void merge_kernel(const float* __restrict__ dbest,
                                                    const int* __restrict__ ibest,
                                                    float* __restrict__ idx_out) {
    int t = blockIdx.x * 256 + threadIdx.x;
    float d0 = dbest[t], d1 = dbest[L_TOK + t];
    int   i0 = ibest[t], i1 = ibest[L_TOK + t];
    idx_out[t] = (float)((d1 < d0) ? i1 : i0);
}

// ---------------------------------------------------------------------------
// Kernel C: z_q_st + per-block f64 loss partials (unchanged).
// ---------------------------------------------------------------------------
__global__ __launch_bounds__(256) void output_kernel(const float* __restrict__ z,
                                                     const float* __restrict__ emb,
                                                     const float* __restrict__ idx_f,
                                                     float* __restrict__ zq_out,
                                                     double* __restrict__ partials) {
    int gid = blockIdx.x * 256 + threadIdx.x;
    int l = gid >> 6;
    int k = gid & 63;
    int idx = (int)idx_f[l];

    float zv = z[gid];
    float ev = emb[(idx << 6) + k];
    float t    = ev - zv;
    float outv = zv + t;
    zq_out[gid] = outv;

    float sq = t * t;

    __shared__ double red[256];
    red[threadIdx.x] = (double)sq;
    __syncthreads();
    for (int s = 128; s > 0; s >>= 1) {
        if (threadIdx.x < s) red[threadIdx.x] += red[threadIdx.x + s];
        __syncthreads();
    }
    if (threadIdx.x == 0) partials[blockIdx.x] = red[0];
}

// ---------------------------------------------------------------------------
// Kernel D: final deterministic reduction (unchanged).
// ---------------------------------------------------------------------------
__global__ __launch_bounds__(256) void loss_kernel(const double* __restrict__ partials,
                                                   float* __restrict__ loss_out) {
    __shared__ double red[256];
    int t = threadIdx.x;
    double s = 0.0;
    for (int i = 0; i < 64; ++i) s += partials[t * 64 + i];
    red[t] = s;
    __syncthreads();
    for (int st = 128; st > 0; st >>= 1) {
        if (t < st) red[t] += red[t + st];
        __syncthreads();
    }
    if (t == 0) {
        double m  = red[0] / (double)(L_TOK * DIM);
        float  mf = (float)m;
        loss_out[0] = 0.25f * mf + mf;
    }
}

extern "C" void kernel_launch(void* const* d_in, const int* in_sizes, int n_in,
                              void* d_out, int out_size, void* d_ws, size_t ws_size,
                              hipStream_t stream) {
    const float* z   = (const float*)d_in[0];
    const float* emb = (const float*)d_in[1];

    float* out   = (float*)d_out;
    float* zq    = out;                 // [0, 4194304)
    float* loss  = out + 4194304;       // [4194304]
    float* idxf  = out + 4194305;       // [4194305, 4259841)

    char* ws = (char*)d_ws;
    float*  esum     = (float*)ws;                      // 4 KB
    double* partials = (double*)(ws + 8192);            // 128 KB
    float*  dbest    = (float*)(ws + 8192 + 131072);    // 2*65536*4 = 512 KB
    int*    ibest    = (int*)(ws + 8192 + 131072 + 524288);  // 512 KB

    esum_kernel  <<<4,     256, 0, stream>>>(emb, esum);
    argmin_kernel<<<512,   512, 0, stream>>>(z, emb, esum, dbest, ibest);
    merge_kernel <<<256,   256, 0, stream>>>(dbest, ibest, idxf);
    output_kernel<<<16384, 256, 0, stream>>>(z, emb, idxf, zq, partials);
    loss_kernel  <<<1,     256, 0, stream>>>(partials, loss);
}

// Round 14
// 140.495 us; speedup vs baseline: 1.4082x; 1.0471x over previous
//
#include <hip/hip_runtime.h>
#include <float.h>

#define L_TOK 65536
#define DIM   64
#define NCODE 1024

// ---------------------------------------------------------------------------
// Kernel A: per-code ||e||^2 (fp32), sequential-k chain.
// ---------------------------------------------------------------------------
__global__ __launch_bounds__(256) void esum_kernel(const float* __restrict__ emb,
                                                   float* __restrict__ esum) {
    int n = blockIdx.x * 256 + threadIdx.x;
    if (n >= NCODE) return;
    const float* e = emb + ((size_t)n << 6);
    float s = 0.f;
#pragma unroll
    for (int k = 0; k < DIM; ++k) s = fmaf(e[k], e[k], s);
    esum[n] = s;
}

// ---------------------------------------------------------------------------
// Kernel B: argmin. Occupancy history (measured):
//   r9:  2tok/lane, 128-tok tile, 40KB, grid 512: 143us. GRID-limited at
//        2 blocks/CU (VGPR 48 allows 8 w/SIMD; LDS allows 3-4 blocks).
//   r11/r13: 64-80KB blocks are single-resident -> 2 w/SIMD -> 158-169us.
//        => usable LDS/CU for concurrency is in [80,128) KB.
// This round: r9's exact body + CODE-HALF split to double the grid:
//   1024 blocks x 512 thr; block b = token-tile (b>>1, 128 tokens, 32KB —
//   merge arrays reuse the z region) x code-half (b&1); wave w covers
//   codes [half*512+64w, +64). VGPR ~48 -> 8 w/SIMD allowed; LDS 32KB ->
//   3-4 blocks/CU; grid 4/CU. Expected 6-8 w/SIMD (1.5-2x r9's hiding);
//   s_load-per-fmac economics unchanged from r9.
// Numerics bitwise-identical to r9/r13 (absmax 0.0): sequential-k fmaf
// chains, d = fmaf(a,-2,zs+esum), ascending strict '<', ascending-wave
// in-block merge, half0-wins cross-half merge == np.argmin first-wins.
// ---------------------------------------------------------------------------
__global__ __launch_bounds__(512, 2) void argmin_kernel(const float* __restrict__ z,
                                                        const float* __restrict__ emb,
                                                        const float* __restrict__ esum,
                                                        float* __restrict__ dbest,
                                                        int* __restrict__ ibest) {
    __shared__ float zl[128 * 64];    // swizzled row-major [tok][k], 32 KB
                                      // (reused for the cross-wave merge)
    const int t    = threadIdx.x;
    const int lane = t & 63;
    const int wid  = __builtin_amdgcn_readfirstlane(t >> 6);
    char* zbytes   = (char*)zl;

    const int tokbase = (blockIdx.x >> 1) * 128;
    const int half    = blockIdx.x & 1;

    // Stage z tile: 128 rows; each thread stages 16 consecutive floats of one
    // row (4 float4s), coalesced global read, swizzled LDS writes.
    {
        const int tok = t >> 2;            // 0..127
        const int kk  = (t & 3) * 16;      // 0,16,32,48
        const int swt = (tok & 15) << 4;
        const float* src = z + ((size_t)(tokbase + tok) << 6) + kk;
        float4 v0 = ((const float4*)src)[0];
        float4 v1 = ((const float4*)src)[1];
        float4 v2 = ((const float4*)src)[2];
        float4 v3 = ((const float4*)src)[3];
        *(float4*)(zbytes + tok * 256 + (((kk +  0) * 4) ^ swt)) = v0;
        *(float4*)(zbytes + tok * 256 + (((kk +  4) * 4) ^ swt)) = v1;
        *(float4*)(zbytes + tok * 256 + (((kk +  8) * 4) ^ swt)) = v2;
        *(float4*)(zbytes + tok * 256 + (((kk + 12) * 4) ^ swt)) = v3;
    }
    __syncthreads();

    const int rbA = lane * 256;            // token A = lane
    const int rbB = rbA + 64 * 256;        // token B = lane + 64
    const int sw  = (lane & 15) << 4;      // (lane+64)&15 == lane&15

    // ||z||^2 per token, sequential k (chunk-ascending, x,y,z,w order).
    float zsA = 0.f, zsB = 0.f;
#pragma unroll
    for (int k0 = 0; k0 < 64; k0 += 4) {
        float4 a = *(const float4*)(zbytes + rbA + ((k0 * 4) ^ sw));
        float4 b = *(const float4*)(zbytes + rbB + ((k0 * 4) ^ sw));
        zsA = fmaf(a.x, a.x, zsA); zsA = fmaf(a.y, a.y, zsA);
        zsA = fmaf(a.z, a.z, zsA); zsA = fmaf(a.w, a.w, zsA);
        zsB = fmaf(b.x, b.x, zsB); zsB = fmaf(b.y, b.y, zsB);
        zsB = fmaf(b.z, b.z, zsB); zsB = fmaf(b.w, b.w, zsB);
    }

    float bestA = FLT_MAX, bestB = FLT_MAX;
    int   biA   = 0,       biB   = 0;
    const int cbase = half * 512 + wid * 64;   // wave-uniform

    for (int c0 = cbase; c0 < cbase + 64; c0 += 8) {
        int szero = 0;
        asm volatile("" : "+s"(szero));    // opaque per-iter def: blocks LICM
        const int rA = rbA + szero;
        const int rB = rbB + szero;

        const float* __restrict__ e0 = emb + ((size_t)(c0 + 0) << 6);
        const float* __restrict__ e1 = emb + ((size_t)(c0 + 1) << 6);
        const float* __restrict__ e2 = emb + ((size_t)(c0 + 2) << 6);
        const float* __restrict__ e3 = emb + ((size_t)(c0 + 3) << 6);
        const float* __restrict__ e4 = emb + ((size_t)(c0 + 4) << 6);
        const float* __restrict__ e5 = emb + ((size_t)(c0 + 5) << 6);
        const float* __restrict__ e6 = emb + ((size_t)(c0 + 6) << 6);
        const float* __restrict__ e7 = emb + ((size_t)(c0 + 7) << 6);
        float a0 = 0.f, a1 = 0.f, a2 = 0.f, a3 = 0.f;
        float a4 = 0.f, a5 = 0.f, a6 = 0.f, a7 = 0.f;
        float b0 = 0.f, b1 = 0.f, b2 = 0.f, b3 = 0.f;
        float b4 = 0.f, b5 = 0.f, b6 = 0.f, b7 = 0.f;
#pragma unroll
        for (int k0 = 0; k0 < 64; k0 += 4) {
            float4 za = *(const float4*)(zbytes + rA + ((k0 * 4) ^ sw));
            float4 zb = *(const float4*)(zbytes + rB + ((k0 * 4) ^ sw));
            float4 f0 = *(const float4*)(e0 + k0);
            float4 f1 = *(const float4*)(e1 + k0);
            float4 f2 = *(const float4*)(e2 + k0);
            float4 f3 = *(const float4*)(e3 + k0);
            float4 f4 = *(const float4*)(e4 + k0);
            float4 f5 = *(const float4*)(e5 + k0);
            float4 f6 = *(const float4*)(e6 + k0);
            float4 f7 = *(const float4*)(e7 + k0);
            a0 = fmaf(za.x, f0.x, a0); a0 = fmaf(za.y, f0.y, a0);
            a0 = fmaf(za.z, f0.z, a0); a0 = fmaf(za.w, f0.w, a0);
            a1 = fmaf(za.x, f1.x, a1); a1 = fmaf(za.y, f1.y, a1);
            a1 = fmaf(za.z, f1.z, a1); a1 = fmaf(za.w, f1.w, a1);
            a2 = fmaf(za.x, f2.x, a2); a2 = fmaf(za.y, f2.y, a2);
            a2 = fmaf(za.z, f2.z, a2); a2 = fmaf(za.w, f2.w, a2);
            a3 = fmaf(za.x, f3.x, a3); a3 = fmaf(za.y, f3.y, a3);
            a3 = fmaf(za.z, f3.z, a3); a3 = fmaf(za.w, f3.w, a3);
            a4 = fmaf(za.x, f4.x, a4); a4 = fmaf(za.y, f4.y, a4);
            a4 = fmaf(za.z, f4.z, a4); a4 = fmaf(za.w, f4.w, a4);
            a5 = fmaf(za.x, f5.x, a5); a5 = fmaf(za.y, f5.y, a5);
            a5 = fmaf(za.z, f5.z, a5); a5 = fmaf(za.w, f5.w, a5);
            a6 = fmaf(za.x, f6.x, a6); a6 = fmaf(za.y, f6.y, a6);
            a6 = fmaf(za.z, f6.z, a6); a6 = fmaf(za.w, f6.w, a6);
            a7 = fmaf(za.x, f7.x, a7); a7 = fmaf(za.y, f7.y, a7);
            a7 = fmaf(za.z, f7.z, a7); a7 = fmaf(za.w, f7.w, a7);
            b0 = fmaf(zb.x, f0.x, b0); b0 = fmaf(zb.y, f0.y, b0);
            b0 = fmaf(zb.z, f0.z, b0); b0 = fmaf(zb.w, f0.w, b0);
            b1 = fmaf(zb.x, f1.x, b1); b1 = fmaf(zb.y, f1.y, b1);
            b1 = fmaf(zb.z, f1.z, b1); b1 = fmaf(zb.w, f1.w, b1);
            b2 = fmaf(zb.x, f2.x, b2); b2 = fmaf(zb.y, f2.y, b2);
            b2 = fmaf(zb.z, f2.z, b2); b2 = fmaf(zb.w, f2.w, b2);
            b3 = fmaf(zb.x, f3.x, b3); b3 = fmaf(zb.y, f3.y, b3);
            b3 = fmaf(zb.z, f3.z, b3); b3 = fmaf(zb.w, f3.w, b3);
            b4 = fmaf(zb.x, f4.x, b4); b4 = fmaf(zb.y, f4.y, b4);
            b4 = fmaf(zb.z, f4.z, b4); b4 = fmaf(zb.w, f4.w, b4);
            b5 = fmaf(zb.x, f5.x, b5); b5 = fmaf(zb.y, f5.y, b5);
            b5 = fmaf(zb.z, f5.z, b5); b5 = fmaf(zb.w, f5.w, b5);
            b6 = fmaf(zb.x, f6.x, b6); b6 = fmaf(zb.y, f6.y, b6);
            b6 = fmaf(zb.z, f6.z, b6); b6 = fmaf(zb.w, f6.w, b6);
            b7 = fmaf(zb.x, f7.x, b7); b7 = fmaf(zb.y, f7.y, b7);
            b7 = fmaf(zb.z, f7.z, b7); b7 = fmaf(zb.w, f7.w, b7);
        }
#pragma unroll
        for (int j = 0; j < 8; ++j) {
            float aj = (j==0?a0:j==1?a1:j==2?a2:j==3?a3:j==4?a4:j==5?a5:j==6?a6:a7);
            float bj = (j==0?b0:j==1?b1:j==2?b2:j==3?b3:j==4?b4:j==5?b5:j==6?b6:b7);
            float es = esum[c0 + j];
            float dA = fmaf(aj, -2.0f, zsA + es);
            float dB = fmaf(bj, -2.0f, zsB + es);
            if (dA < bestA) { bestA = dA; biA = c0 + j; }
            if (dB < bestB) { bestB = dB; biB = c0 + j; }
        }
    }

    // Cross-wave merge: reuse the z LDS region (all z reads are done).
    __syncthreads();
    float* sbf = zl;                  // [8][128] floats
    int*   sif = (int*)(zl + 1024);   // [8][128] ints
    sbf[wid * 128 + lane]      = bestA;  sif[wid * 128 + lane]      = biA;
    sbf[wid * 128 + lane + 64] = bestB;  sif[wid * 128 + lane + 64] = biB;
    __syncthreads();

    if (t < 128) {
        float b = sbf[t];
        int   i = sif[t];
#pragma unroll
        for (int w = 1; w < 8; ++w) {
            float ob = sbf[w * 128 + t];
            int   oi = sif[w * 128 + t];
            if (ob < b || (ob == b && oi < i)) { b = ob; i = oi; }
        }
        dbest[half * L_TOK + tokbase + t] = b;
        ibest[half * L_TOK + tokbase + t] = i;
    }
}

// ---------------------------------------------------------------------------
// Kernel B2: merge the two code-halves. half0 = codes [0,512) so on ties
// half0 wins == lowest index == np.argmin first-wins.
// ---------------------------------------------------------------------------
__global__ __launch_bounds__(256) void merge_kernel(const float* __restrict__ dbest,
                                                    const int* __restrict__ ibest,
                                                    float* __restrict__ idx_out) {
    int t = blockIdx.x * 256 + threadIdx.x;
    float d0 = dbest[t], d1 = dbest[L_TOK + t];
    int   i0 = ibest[t], i1 = ibest[L_TOK + t];
    idx_out[t] = (float)((d1 < d0) ? i1 : i0);
}

// ---------------------------------------------------------------------------
// Kernel C: z_q_st + per-block f64 loss partials (unchanged).
// ---------------------------------------------------------------------------
__global__ __launch_bounds__(256) void output_kernel(const float* __restrict__ z,
                                                     const float* __restrict__ emb,
                                                     const float* __restrict__ idx_f,
                                                     float* __restrict__ zq_out,
                                                     double* __restrict__ partials) {
    int gid = blockIdx.x * 256 + threadIdx.x;
    int l = gid >> 6;
    int k = gid & 63;
    int idx = (int)idx_f[l];

    float zv = z[gid];
    float ev = emb[(idx << 6) + k];
    float t    = ev - zv;
    float outv = zv + t;
    zq_out[gid] = outv;

    float sq = t * t;

    __shared__ double red[256];
    red[threadIdx.x] = (double)sq;
    __syncthreads();
    for (int s = 128; s > 0; s >>= 1) {
        if (threadIdx.x < s) red[threadIdx.x] += red[threadIdx.x + s];
        __syncthreads();
    }
    if (threadIdx.x == 0) partials[blockIdx.x] = red[0];
}

// ---------------------------------------------------------------------------
// Kernel D: final deterministic reduction (unchanged).
// ---------------------------------------------------------------------------
__global__ __launch_bounds__(256) void loss_kernel(const double* __restrict__ partials,
                                                   float* __restrict__ loss_out) {
    __shared__ double red[256];
    int t = threadIdx.x;
    double s = 0.0;
    for (int i = 0; i < 64; ++i) s += partials[t * 64 + i];
    red[t] = s;
    __syncthreads();
    for (int st = 128; st > 0; st >>= 1) {
        if (t < st) red[t] += red[t + st];
        __syncthreads();
    }
    if (t == 0) {
        double m  = red[0] / (double)(L_TOK * DIM);
        float  mf = (float)m;
        loss_out[0] = 0.25f * mf + mf;
    }
}

extern "C" void kernel_launch(void* const* d_in, const int* in_sizes, int n_in,
                              void* d_out, int out_size, void* d_ws, size_t ws_size,
                              hipStream_t stream) {
    const float* z   = (const float*)d_in[0];
    const float* emb = (const float*)d_in[1];

    float* out   = (float*)d_out;
    float* zq    = out;                 // [0, 4194304)
    float* loss  = out + 4194304;       // [4194304]
    float* idxf  = out + 4194305;       // [4194305, 4259841)

    char* ws = (char*)d_ws;
    float*  esum     = (float*)ws;                      // 4 KB
    double* partials = (double*)(ws + 8192);            // 128 KB
    float*  dbest    = (float*)(ws + 8192 + 131072);    // 512 KB
    int*    ibest    = (int*)(ws + 8192 + 131072 + 524288);  // 512 KB

    esum_kernel  <<<4,     256, 0, stream>>>(emb, esum);
    argmin_kernel<<<1024,  512, 0, stream>>>(z, emb, esum, dbest, ibest);
    merge_kernel <<<256,   256, 0, stream>>>(dbest, ibest, idxf);
    output_kernel<<<16384, 256, 0, stream>>>(z, emb, idxf, zq, partials);
    loss_kernel  <<<1,     256, 0, stream>>>(partials, loss);
}